// Round 7
// baseline (269.993 us; speedup 1.0000x reference)
//
#include <hip/hip_runtime.h>
#include <stdint.h>

// TreeDecoder on MI355X. B=32, CN=1024, DEG=2, IN=OUT=128, NODES={1,16,128,1024}.
//
// R12: force the W prefetch. R11's counters exposed tree_main as latency-bound
// (80us, 19% HBM, 4% MfmaUtil, VGPR_Count=68): the compiler SANK the depth-4
// LOADW prefetch to its uses (68 regs can't hold 64 prefetched floats), so
// every WBODY ate ~700cy of raw HBM latency. R12 issues ALL 8 W tiles (128
// scalar dwords, 131KB/block) BEFORE t-staging and pins them with
// __builtin_amdgcn_sched_barrier(0); the staging barrier's vmcnt(0) drains
// them into registers, and phases A+B run register-resident with zero W
// stalls. Bit-identical math; only issue order changes. Expect VGPR >= ~170.

using short8   = __attribute__((ext_vector_type(8))) short;   // 8 x bf16
using floatx16 = __attribute__((ext_vector_type(16))) float;  // 32x32 acc

__device__ __forceinline__ unsigned short f2bf(float f) {
    unsigned int u = __builtin_bit_cast(unsigned int, f);
    return (unsigned short)((u + 0x8000u) >> 16);
}

// ws layout (float offsets).
//  P      [16][16512]        @ 0       (264192 fl)
//  Fbias  [128]              @ 524288
//  FfusedBF [16][128][8] u16 @ 524416  (8192 fl)
//  UwBF [4][16][128][8] u16  @ 532608  (32768 fl)
#define FB_OFF  524288
#define FF_OFF  524416
#define UW_OFF  532608

// ---- ffused stage 1: 80-MAC partials, overwrite-only. grid(8,129) --------
__global__ __launch_bounds__(256) void ffused_p1(
    const float* __restrict__ Fw0, const float* __restrict__ Fb0,
    const float* __restrict__ Fw1, float* __restrict__ P)
{
    const int kc = blockIdx.x;            // 0..7
    const int i  = blockIdx.y;            // 0..128 (128 = bias row)
    const int j  = threadIdx.x & 127;
    const int il = threadIdx.x >> 7;
    const int k0 = kc * 160 + il * 80;
    const float* __restrict__ src = (i < 128) ? (Fw0 + (size_t)i * 1280) : Fb0;
    float acc = 0.f;
    #pragma unroll 8
    for (int kk = 0; kk < 80; ++kk)
        acc += src[k0 + kk] * Fw1[(size_t)(k0 + kk) * 128 + j];
    P[(size_t)(kc * 2 + il) * 16512 + i * 128 + j] = acc;
}

// ---- prep2: blocks 0..64 = ffused reduce -> FfusedBF/Fbias;
//             blocks 65..128 = Uw cat -> bf16 B-frag layout ------------------
__global__ __launch_bounds__(256) void prep2(
    const float* __restrict__ P, const float* __restrict__ Fb1,
    const float* __restrict__ Uw0, const float* __restrict__ Uw1,
    const float* __restrict__ Uw2, const float* __restrict__ Uw3,
    unsigned short* __restrict__ FfusedBF, float* __restrict__ Fbias,
    unsigned short* __restrict__ UwBF)
{
    if (blockIdx.x < 65) {
        const int idx = blockIdx.x * 256 + threadIdx.x;
        if (idx >= 16512) return;
        const int i = idx >> 7, j = idx & 127;
        float s = 0.f;
        #pragma unroll
        for (int p = 0; p < 16; ++p) s += P[(size_t)p * 16512 + idx];
        if (i < 128) FfusedBF[(((i >> 3) * 128) + j) * 8 + (i & 7)] = f2bf(s);
        else         Fbias[j] = s + Fb1[j];
    } else {
        const int bx  = blockIdx.x - 65;
        const int mat = bx >> 4;
        const int kg  = bx & 15;
        const float* __restrict__ Uw = (mat == 0) ? Uw0 : (mat == 1) ? Uw1
                                     : (mat == 2) ? Uw2 : Uw3;
        const int col = threadIdx.x & 127;
        const int kh  = threadIdx.x >> 7;
        #pragma unroll
        for (int q = 0; q < 4; ++q) {
            const int kk = kh * 4 + q;
            const float v = Uw[(size_t)(kg * 8 + kk) * 128 + col];
            UwBF[(((size_t)(mat * 16 + kg) * 128) + col) * 8 + kk] = f2bf(v);
        }
    }
}

// ---------------- main: one block per node ---------------------------------
__global__ __launch_bounds__(256, 2) void tree_main(
    const float* __restrict__ t0, const float* __restrict__ t1,
    const float* __restrict__ t2, const float* __restrict__ t3,
    const float* __restrict__ Ub0, const float* __restrict__ Ub1,
    const float* __restrict__ Ub2, const float* __restrict__ Ub3,
    const float* __restrict__ Wup, const float* __restrict__ bbias,
    const unsigned short* __restrict__ FfusedBF,
    const unsigned short* __restrict__ UwBF,
    const float* __restrict__ Fbias,
    float* __restrict__ out)
{
    const int n    = blockIdx.x;
    const int tid  = threadIdx.x;
    const int w    = tid >> 6;
    const int lane = tid & 63;
    const int l31  = lane & 31;
    const int half = lane >> 5;
    const int colq = w * 32 + l31;
    const int i2   = n >> 3;

    // Alds [64 kg][33 b-pad][8 j] u16 = 33792B; Ulds [16][65][8] u16 (16640B)
    // overlays it after the K-loop.
    __shared__ __align__(16) unsigned char smem_raw[64 * 33 * 8 * 2];
    unsigned short* Alds = (unsigned short*)smem_raw;
    unsigned short* Ulds = (unsigned short*)smem_raw;

    // ---- issue the ENTIRE W tile (8 k-tiles, 128 dwords/thread-slice) ----
    // Pinned by sched_barrier(0) so the scheduler cannot sink these to their
    // phase-B uses (R11: VGPR=68 proved the old depth-4 prefetch was sunk).
    const float* __restrict__ Wbase =
        Wup + (size_t)n * 32768 + (half * 8) * 256 + w * 64 + l31;
    float W0a[8], W0b[8], W1a[8], W1b[8], W2a[8], W2b[8], W3a[8], W3b[8],
          W4a[8], W4b[8], W5a[8], W5b[8], W6a[8], W6b[8], W7a[8], W7b[8];
#define LOADW(P0, P1, WT) \
    { const float* __restrict__ wp = Wbase + (WT) * 16 * 256; \
      _Pragma("unroll") \
      for (int jj = 0; jj < 8; ++jj) { P0[jj] = wp[jj * 256]; P1[jj] = wp[32 + jj * 256]; } }
    LOADW(W0a, W0b, 0) LOADW(W1a, W1b, 1) LOADW(W2a, W2b, 2) LOADW(W3a, W3b, 3)
    LOADW(W4a, W4b, 4) LOADW(W5a, W5b, 5) LOADW(W6a, W6b, 6) LOADW(W7a, W7b, 7)
    __builtin_amdgcn_sched_barrier(0);

    // ---- stage t0..t3 rows (32 b x 128 k each) coalesced -> A-frag layout -
    #pragma unroll
    for (int mi = 0; mi < 4; ++mi) {
        const float* __restrict__ base = (mi == 0) ? t0 : (mi == 1) ? t1
                                       : (mi == 2) ? t2 : t3;
        #pragma unroll
        for (int i = 0; i < 4; ++i) {
            const int idx = i * 256 + tid;      // 0..1023 float4s
            const int b   = idx >> 5;
            const int q   = idx & 31;
            int row;
            if      (mi == 0) row = b;
            else if (mi == 1) row = b * 16 + (i2 >> 3);
            else if (mi == 2) row = b * 128 + i2;
            else              row = b * 1024 + n;
            const float4 v = *reinterpret_cast<const float4*>(
                base + (size_t)row * 128 + q * 4);
            ushort4 u;
            u.x = f2bf(v.x); u.y = f2bf(v.y); u.z = f2bf(v.z); u.w = f2bf(v.w);
            *reinterpret_cast<ushort4*>(
                &Alds[((mi * 16 + (q >> 1)) * 33 + b) * 8 + (q & 1) * 4]) = u;
        }
    }
    __syncthreads();    // vmcnt(0): W stream + staging fully landed here

    floatx16 qacc, accT0, accT1;
    #pragma unroll
    for (int r = 0; r < 16; ++r) { qacc[r] = 0.f; accT0[r] = 0.f; accT1[r] = 0.f; }

    // ---- phase A: anc = t0@Uw0 + t1@Uw1 + t2@Uw2 (kg 0..47) --------------
    #pragma unroll
    for (int ks = 0; ks < 24; ++ks) {
        const int kg = 2 * ks + half;
        const short8 a  = *reinterpret_cast<const short8*>(&Alds[(kg * 33 + l31) * 8]);
        const short8 bf = *reinterpret_cast<const short8*>(
            &UwBF[((size_t)kg * 128 + colq) * 8]);
        qacc = __builtin_amdgcn_mfma_f32_32x32x16_bf16(a, bf, qacc, 0, 0, 0);
    }

    // ---- phase B: + t3@Uw3 (qacc) and U^T = W^T @ t3^T (accT0/1) ---------
    // All W operands already register-resident; zero VMEM in this phase.
#define WBODY(P0, P1, WT) \
    { const int kg = 48 + 2 * (WT) + half; \
      const short8 a  = *reinterpret_cast<const short8*>(&Alds[(kg * 33 + l31) * 8]); \
      const short8 bf = *reinterpret_cast<const short8*>( \
          &UwBF[((size_t)kg * 128 + colq) * 8]); \
      qacc = __builtin_amdgcn_mfma_f32_32x32x16_bf16(a, bf, qacc, 0, 0, 0); \
      short8 a0, a1; \
      _Pragma("unroll") \
      for (int jj = 0; jj < 8; ++jj) { \
          a0[jj] = (short)f2bf(P0[jj]); a1[jj] = (short)f2bf(P1[jj]); } \
      accT0 = __builtin_amdgcn_mfma_f32_32x32x16_bf16(a0, a, accT0, 0, 0, 0); \
      accT1 = __builtin_amdgcn_mfma_f32_32x32x16_bf16(a1, a, accT1, 0, 0, 0); }

    WBODY(W0a, W0b, 0)
    WBODY(W1a, W1b, 1)
    WBODY(W2a, W2b, 2)
    WBODY(W3a, W3b, 3)
    WBODY(W4a, W4b, 4)
    WBODY(W5a, W5b, 5)
    WBODY(W6a, W6b, 6)
    WBODY(W7a, W7b, 7)

    __syncthreads();     // all Alds reads done before Ulds overlays

    // ---- U^T accs -> Ulds in GEMM3 A-frag layout (r2 = d*32 + batch) -----
    #pragma unroll
    for (int tt = 0; tt < 2; ++tt) {
        const floatx16 Av = tt ? accT1 : accT0;
        #pragma unroll
        for (int r = 0; r < 16; ++r) {
            const int cm = w * 64 + tt * 32 + ((r & 3) + 8 * (r >> 2) + 4 * half);
            const int d  = cm >> 7;
            const int cp = cm & 127;
            Ulds[(((cp >> 3) * 65) + d * 32 + l31) * 8 + (cp & 7)] = f2bf(Av[r]);
        }
    }
    __syncthreads();

    // ---- prefetch epilogue operands (hide under GEMM3's 16 MFMAs) --------
    const float ubsum = Ub0[colq] + Ub1[colq] + Ub2[colq] + Ub3[colq] + Fbias[colq];
    const float bb0 = bbias[(size_t)(2 * n + 0) * 128 + colq];
    const float bb1 = bbias[(size_t)(2 * n + 1) * 128 + colq];

    // ---- GEMM 3: out = U2 @ Ffused  (M64 N128 K128) ----------------------
    floatx16 o0, o1;
    #pragma unroll
    for (int r = 0; r < 16; ++r) { o0[r] = 0.f; o1[r] = 0.f; }
    #pragma unroll
    for (int ks = 0; ks < 8; ++ks) {
        const int kg2 = 2 * ks + half;
        const short8 a0 = *reinterpret_cast<const short8*>(&Ulds[(kg2 * 65 + l31) * 8]);
        const short8 a1 = *reinterpret_cast<const short8*>(&Ulds[(kg2 * 65 + 32 + l31) * 8]);
        const short8 bf = *reinterpret_cast<const short8*>(
            &FfusedBF[(((size_t)kg2 * 128) + colq) * 8]);
        o0 = __builtin_amdgcn_mfma_f32_32x32x16_bf16(a0, bf, o0, 0, 0, 0);
        o1 = __builtin_amdgcn_mfma_f32_32x32x16_bf16(a1, bf, o1, 0, 0, 0);
    }

    // ---- epilogue: + qacc(anc, all 4 depths) + biases, LeakyReLU, store --
    #pragma unroll
    for (int r = 0; r < 16; ++r) {
        const int brow = (r & 3) + 8 * (r >> 2) + 4 * half;   // batch
        const float addc = qacc[r] + ubsum;
        float v0 = o0[r] + addc + bb0;
        float v1 = o1[r] + addc + bb1;
        v0 = (v0 >= 0.f) ? v0 : 0.2f * v0;
        v1 = (v1 >= 0.f) ? v1 : 0.2f * v1;
        const size_t idx0 = ((size_t)brow * 2048 + 2 * n) * 128 + colq;
        out[idx0]       = v0;
        out[idx0 + 128] = v1;
    }
}

extern "C" void kernel_launch(void* const* d_in, const int* in_sizes, int n_in,
                              void* d_out, int out_size, void* d_ws, size_t ws_size,
                              hipStream_t stream) {
    const float* t0  = (const float*)d_in[0];
    const float* t1  = (const float*)d_in[1];
    const float* t2  = (const float*)d_in[2];
    const float* t3  = (const float*)d_in[3];
    const float* Uw0 = (const float*)d_in[4];
    const float* Ub0 = (const float*)d_in[5];
    const float* Uw1 = (const float*)d_in[6];
    const float* Ub1 = (const float*)d_in[7];
    const float* Uw2 = (const float*)d_in[8];
    const float* Ub2 = (const float*)d_in[9];
    const float* Uw3 = (const float*)d_in[10];
    const float* Ub3 = (const float*)d_in[11];
    const float* Wup = (const float*)d_in[12];
    const float* Fw0 = (const float*)d_in[13];
    const float* Fb0 = (const float*)d_in[14];
    const float* Fw1 = (const float*)d_in[15];
    const float* Fb1 = (const float*)d_in[16];
    const float* bb  = (const float*)d_in[17];

    float* ws = (float*)d_ws;
    float* P              = ws;                  // partials (dead after prep2)
    float* Fbias          = ws + FB_OFF;
    unsigned short* FfBF  = (unsigned short*)(ws + FF_OFF);
    unsigned short* UwBF  = (unsigned short*)(ws + UW_OFF);

    ffused_p1<<<dim3(8, 129), 256, 0, stream>>>(Fw0, Fb0, Fw1, P);
    prep2<<<129, 256, 0, stream>>>(P, Fb1, Uw0, Uw1, Uw2, Uw3, FfBF, Fbias, UwBF);
    tree_main<<<1024, 256, 0, stream>>>(t0, t1, t2, t3,
                                        Ub0, Ub1, Ub2, Ub3,
                                        Wup, bb, FfBF, UwBF,
                                        Fbias, (float*)d_out);
}

// Round 8
// 263.850 us; speedup vs baseline: 1.0233x; 1.0233x over previous
//
#include <hip/hip_runtime.h>
#include <stdint.h>

// TreeDecoder on MI355X. B=32, CN=1024, DEG=2, IN=OUT=128, NODES={1,16,128,1024}.
//
// R13: W through LDS via global_load_lds_dwordx4. Register-resident W
// prefetch failed 3x (R6/R9: compiler sank loads, VGPR=68 proved it; R12:
// sched_barrier pin gave no win -- spill/resplit at 128 live floats).
// gload_lds sidesteps it: loads write LDS (nothing to sink), the W stream
// becomes linear 16KB tile copies (1KB/instr), and frags come from LDS with
// conflict-free ds_read_b32. Double-buffered: tiles 0,1 issued before
// t-staging (land at the existing barrier); loop = compute(t) -> barrier
// (compiler vmcnt(0) drains tile t+1) -> issue tile t+2 into buf[t&1].
// f2bf + MFMA order untouched -> bit-identical numerics.

using short8   = __attribute__((ext_vector_type(8))) short;   // 8 x bf16
using floatx16 = __attribute__((ext_vector_type(16))) float;  // 32x32 acc

__device__ __forceinline__ unsigned short f2bf(float f) {
    unsigned int u = __builtin_bit_cast(unsigned int, f);
    return (unsigned short)((u + 0x8000u) >> 16);
}

// ws layout (float offsets).
//  P      [16][16512]        @ 0       (264192 fl)
//  Fbias  [128]              @ 524288
//  FfusedBF [16][128][8] u16 @ 524416  (8192 fl)
//  UwBF [4][16][128][8] u16  @ 532608  (32768 fl)
#define FB_OFF  524288
#define FF_OFF  524416
#define UW_OFF  532608

// ---- ffused stage 1: 80-MAC partials, overwrite-only. grid(8,129) --------
__global__ __launch_bounds__(256) void ffused_p1(
    const float* __restrict__ Fw0, const float* __restrict__ Fb0,
    const float* __restrict__ Fw1, float* __restrict__ P)
{
    const int kc = blockIdx.x;            // 0..7
    const int i  = blockIdx.y;            // 0..128 (128 = bias row)
    const int j  = threadIdx.x & 127;
    const int il = threadIdx.x >> 7;
    const int k0 = kc * 160 + il * 80;
    const float* __restrict__ src = (i < 128) ? (Fw0 + (size_t)i * 1280) : Fb0;
    float acc = 0.f;
    #pragma unroll 8
    for (int kk = 0; kk < 80; ++kk)
        acc += src[k0 + kk] * Fw1[(size_t)(k0 + kk) * 128 + j];
    P[(size_t)(kc * 2 + il) * 16512 + i * 128 + j] = acc;
}

// ---- prep2: blocks 0..64 = ffused reduce -> FfusedBF/Fbias;
//             blocks 65..128 = Uw cat -> bf16 B-frag layout ------------------
__global__ __launch_bounds__(256) void prep2(
    const float* __restrict__ P, const float* __restrict__ Fb1,
    const float* __restrict__ Uw0, const float* __restrict__ Uw1,
    const float* __restrict__ Uw2, const float* __restrict__ Uw3,
    unsigned short* __restrict__ FfusedBF, float* __restrict__ Fbias,
    unsigned short* __restrict__ UwBF)
{
    if (blockIdx.x < 65) {
        const int idx = blockIdx.x * 256 + threadIdx.x;
        if (idx >= 16512) return;
        const int i = idx >> 7, j = idx & 127;
        float s = 0.f;
        #pragma unroll
        for (int p = 0; p < 16; ++p) s += P[(size_t)p * 16512 + idx];
        if (i < 128) FfusedBF[(((i >> 3) * 128) + j) * 8 + (i & 7)] = f2bf(s);
        else         Fbias[j] = s + Fb1[j];
    } else {
        const int bx  = blockIdx.x - 65;
        const int mat = bx >> 4;
        const int kg  = bx & 15;
        const float* __restrict__ Uw = (mat == 0) ? Uw0 : (mat == 1) ? Uw1
                                     : (mat == 2) ? Uw2 : Uw3;
        const int col = threadIdx.x & 127;
        const int kh  = threadIdx.x >> 7;
        #pragma unroll
        for (int q = 0; q < 4; ++q) {
            const int kk = kh * 4 + q;
            const float v = Uw[(size_t)(kg * 8 + kk) * 128 + col];
            UwBF[(((size_t)(mat * 16 + kg) * 128) + col) * 8 + kk] = f2bf(v);
        }
    }
}

// ---------------- main: one block per node ---------------------------------
__global__ __launch_bounds__(256, 2) void tree_main(
    const float* __restrict__ t0, const float* __restrict__ t1,
    const float* __restrict__ t2, const float* __restrict__ t3,
    const float* __restrict__ Ub0, const float* __restrict__ Ub1,
    const float* __restrict__ Ub2, const float* __restrict__ Ub3,
    const float* __restrict__ Wup, const float* __restrict__ bbias,
    const unsigned short* __restrict__ FfusedBF,
    const unsigned short* __restrict__ UwBF,
    const float* __restrict__ Fbias,
    float* __restrict__ out)
{
    const int n    = blockIdx.x;
    const int tid  = threadIdx.x;
    const int w    = tid >> 6;
    const int lane = tid & 63;
    const int l31  = lane & 31;
    const int half = lane >> 5;
    const int colq = w * 32 + l31;
    const int i2   = n >> 3;

    // smem: [Alds 33792B][wbuf0 16384B][wbuf1 16384B] = 66560B.
    // Ulds (16640B) overlays Alds after phase B.
    __shared__ __align__(16) unsigned char smem_raw[33792 + 2 * 16384];
    unsigned short* Alds = (unsigned short*)smem_raw;
    unsigned short* Ulds = (unsigned short*)smem_raw;
    float* wbuf0 = (float*)(smem_raw + 33792);
    float* wbuf1 = (float*)(smem_raw + 33792 + 16384);

    // ---- W tile issue: tile T (16 k-rows x 256 cols fp32 = 16KB), linear
    // copy global->LDS. Per wave 4 chunks of 1KB; LDS dest wave-uniform,
    // global src per-lane (16B each). Cannot be sunk: writes LDS.
    const float* __restrict__ Wtile = Wup + (size_t)n * 32768;
#define ISSUE_W(T, WB) \
    { _Pragma("unroll") \
      for (int q = 0; q < 4; ++q) { \
        const int chunk = (tid >> 6) * 4 + q; \
        const float* gp = Wtile + (T) * 4096 + chunk * 256 + (tid & 63) * 4; \
        float* lp = (WB) + chunk * 256; \
        __builtin_amdgcn_global_load_lds( \
            (const __attribute__((address_space(1))) unsigned int*)gp, \
            (__attribute__((address_space(3))) unsigned int*)lp, 16, 0, 0); \
      } }

    ISSUE_W(0, wbuf0)
    ISSUE_W(1, wbuf1)

    // ---- stage t0..t3 rows (32 b x 128 k each) coalesced -> A-frag layout -
    #pragma unroll
    for (int mi = 0; mi < 4; ++mi) {
        const float* __restrict__ base = (mi == 0) ? t0 : (mi == 1) ? t1
                                       : (mi == 2) ? t2 : t3;
        #pragma unroll
        for (int i = 0; i < 4; ++i) {
            const int idx = i * 256 + tid;      // 0..1023 float4s
            const int b   = idx >> 5;
            const int q   = idx & 31;
            int row;
            if      (mi == 0) row = b;
            else if (mi == 1) row = b * 16 + (i2 >> 3);
            else if (mi == 2) row = b * 128 + i2;
            else              row = b * 1024 + n;
            const float4 v = *reinterpret_cast<const float4*>(
                base + (size_t)row * 128 + q * 4);
            ushort4 u;
            u.x = f2bf(v.x); u.y = f2bf(v.y); u.z = f2bf(v.z); u.w = f2bf(v.w);
            *reinterpret_cast<ushort4*>(
                &Alds[((mi * 16 + (q >> 1)) * 33 + b) * 8 + (q & 1) * 4]) = u;
        }
    }
    __syncthreads();    // vmcnt(0): W tiles 0,1 + staging fully landed

    floatx16 qacc, accT0, accT1;
    #pragma unroll
    for (int r = 0; r < 16; ++r) { qacc[r] = 0.f; accT0[r] = 0.f; accT1[r] = 0.f; }

    // ---- phase A: anc = t0@Uw0 + t1@Uw1 + t2@Uw2 (kg 0..47) --------------
    #pragma unroll
    for (int ks = 0; ks < 24; ++ks) {
        const int kg = 2 * ks + half;
        const short8 a  = *reinterpret_cast<const short8*>(&Alds[(kg * 33 + l31) * 8]);
        const short8 bf = *reinterpret_cast<const short8*>(
            &UwBF[((size_t)kg * 128 + colq) * 8]);
        qacc = __builtin_amdgcn_mfma_f32_32x32x16_bf16(a, bf, qacc, 0, 0, 0);
    }

    // ---- phase B: + t3@Uw3 (qacc) and U^T = W^T @ t3^T (accT0/1) ---------
    // W frags from LDS: 16 ds_read_b32, banks = l31 -> conflict-free.
#define WBODY_L(WT, WB) \
    { const int kg = 48 + 2 * (WT) + half; \
      const short8 a  = *reinterpret_cast<const short8*>(&Alds[(kg * 33 + l31) * 8]); \
      const short8 bf = *reinterpret_cast<const short8*>( \
          &UwBF[((size_t)kg * 128 + colq) * 8]); \
      qacc = __builtin_amdgcn_mfma_f32_32x32x16_bf16(a, bf, qacc, 0, 0, 0); \
      short8 a0, a1; \
      _Pragma("unroll") \
      for (int jj = 0; jj < 8; ++jj) { \
          a0[jj] = (short)f2bf((WB)[(half * 8 + jj) * 256 + w * 64 + l31]); \
          a1[jj] = (short)f2bf((WB)[(half * 8 + jj) * 256 + w * 64 + 32 + l31]); } \
      accT0 = __builtin_amdgcn_mfma_f32_32x32x16_bf16(a0, a, accT0, 0, 0, 0); \
      accT1 = __builtin_amdgcn_mfma_f32_32x32x16_bf16(a1, a, accT1, 0, 0, 0); }

    WBODY_L(0, wbuf0) __syncthreads(); ISSUE_W(2, wbuf0)
    WBODY_L(1, wbuf1) __syncthreads(); ISSUE_W(3, wbuf1)
    WBODY_L(2, wbuf0) __syncthreads(); ISSUE_W(4, wbuf0)
    WBODY_L(3, wbuf1) __syncthreads(); ISSUE_W(5, wbuf1)
    WBODY_L(4, wbuf0) __syncthreads(); ISSUE_W(6, wbuf0)
    WBODY_L(5, wbuf1) __syncthreads(); ISSUE_W(7, wbuf1)
    WBODY_L(6, wbuf0) __syncthreads();
    WBODY_L(7, wbuf1)

    __syncthreads();     // all Alds reads done before Ulds overlays

    // ---- U^T accs -> Ulds in GEMM3 A-frag layout (r2 = d*32 + batch) -----
    #pragma unroll
    for (int tt = 0; tt < 2; ++tt) {
        const floatx16 Av = tt ? accT1 : accT0;
        #pragma unroll
        for (int r = 0; r < 16; ++r) {
            const int cm = w * 64 + tt * 32 + ((r & 3) + 8 * (r >> 2) + 4 * half);
            const int d  = cm >> 7;
            const int cp = cm & 127;
            Ulds[(((cp >> 3) * 65) + d * 32 + l31) * 8 + (cp & 7)] = f2bf(Av[r]);
        }
    }
    __syncthreads();

    // ---- prefetch epilogue operands (hide under GEMM3's 16 MFMAs) --------
    const float ubsum = Ub0[colq] + Ub1[colq] + Ub2[colq] + Ub3[colq] + Fbias[colq];
    const float bb0 = bbias[(size_t)(2 * n + 0) * 128 + colq];
    const float bb1 = bbias[(size_t)(2 * n + 1) * 128 + colq];

    // ---- GEMM 3: out = U2 @ Ffused  (M64 N128 K128) ----------------------
    floatx16 o0, o1;
    #pragma unroll
    for (int r = 0; r < 16; ++r) { o0[r] = 0.f; o1[r] = 0.f; }
    #pragma unroll
    for (int ks = 0; ks < 8; ++ks) {
        const int kg2 = 2 * ks + half;
        const short8 a0 = *reinterpret_cast<const short8*>(&Ulds[(kg2 * 65 + l31) * 8]);
        const short8 a1 = *reinterpret_cast<const short8*>(&Ulds[(kg2 * 65 + 32 + l31) * 8]);
        const short8 bf = *reinterpret_cast<const short8*>(
            &FfusedBF[(((size_t)kg2 * 128) + colq) * 8]);
        o0 = __builtin_amdgcn_mfma_f32_32x32x16_bf16(a0, bf, o0, 0, 0, 0);
        o1 = __builtin_amdgcn_mfma_f32_32x32x16_bf16(a1, bf, o1, 0, 0, 0);
    }

    // ---- epilogue: + qacc(anc, all 4 depths) + biases, LeakyReLU, store --
    #pragma unroll
    for (int r = 0; r < 16; ++r) {
        const int brow = (r & 3) + 8 * (r >> 2) + 4 * half;   // batch
        const float addc = qacc[r] + ubsum;
        float v0 = o0[r] + addc + bb0;
        float v1 = o1[r] + addc + bb1;
        v0 = (v0 >= 0.f) ? v0 : 0.2f * v0;
        v1 = (v1 >= 0.f) ? v1 : 0.2f * v1;
        const size_t idx0 = ((size_t)brow * 2048 + 2 * n) * 128 + colq;
        out[idx0]       = v0;
        out[idx0 + 128] = v1;
    }
}

extern "C" void kernel_launch(void* const* d_in, const int* in_sizes, int n_in,
                              void* d_out, int out_size, void* d_ws, size_t ws_size,
                              hipStream_t stream) {
    const float* t0  = (const float*)d_in[0];
    const float* t1  = (const float*)d_in[1];
    const float* t2  = (const float*)d_in[2];
    const float* t3  = (const float*)d_in[3];
    const float* Uw0 = (const float*)d_in[4];
    const float* Ub0 = (const float*)d_in[5];
    const float* Uw1 = (const float*)d_in[6];
    const float* Ub1 = (const float*)d_in[7];
    const float* Uw2 = (const float*)d_in[8];
    const float* Ub2 = (const float*)d_in[9];
    const float* Uw3 = (const float*)d_in[10];
    const float* Ub3 = (const float*)d_in[11];
    const float* Wup = (const float*)d_in[12];
    const float* Fw0 = (const float*)d_in[13];
    const float* Fb0 = (const float*)d_in[14];
    const float* Fw1 = (const float*)d_in[15];
    const float* Fb1 = (const float*)d_in[16];
    const float* bb  = (const float*)d_in[17];

    float* ws = (float*)d_ws;
    float* P              = ws;                  // partials (dead after prep2)
    float* Fbias          = ws + FB_OFF;
    unsigned short* FfBF  = (unsigned short*)(ws + FF_OFF);
    unsigned short* UwBF  = (unsigned short*)(ws + UW_OFF);

    ffused_p1<<<dim3(8, 129), 256, 0, stream>>>(Fw0, Fb0, Fw1, P);
    prep2<<<129, 256, 0, stream>>>(P, Fb1, Uw0, Uw1, Uw2, Uw3, FfBF, Fbias, UwBF);
    tree_main<<<1024, 256, 0, stream>>>(t0, t1, t2, t3,
                                        Ub0, Ub1, Ub2, Ub3,
                                        Wup, bb, FfBF, UwBF,
                                        Fbias, (float*)d_out);
}